// Round 9
// baseline (585.119 us; speedup 1.0000x reference)
//
#include <hip/hip_runtime.h>
#include <hip/hip_bf16.h>
#include <cstdint>

#define S 8
#define NTOT 20000
#define NSUB 4000
#define F 128
#define HID 64
#define NH 8
#define DH 8
#define KSPL 2016   // split-K boundary: 2016 (63 steps) / 1984 (62 steps), BK=32

typedef __attribute__((ext_vector_type(8))) short bf16x8;
typedef __attribute__((ext_vector_type(4))) short bf16x4;
typedef __attribute__((ext_vector_type(4))) float f32x4;

__device__ __forceinline__ short f2bf(float f) {
  union { __hip_bfloat16 h; short s; } u;
  u.h = __float2bfloat16(f);
  return u.s;
}

__device__ __forceinline__ void gload16(const void* gsrc, void* ldst) {
  __builtin_amdgcn_global_load_lds(
      (const __attribute__((address_space(1))) void*)gsrc,
      (__attribute__((address_space(3))) void*)ldst, 16, 0, 0);
}

// ---------------- position map
__global__ void k_pos_init(int* __restrict__ posIdx) {
  int t = blockIdx.x * 256 + threadIdx.x;
  if (t < NTOT * S) posIdx[t] = -1;
}

__global__ void k_pos_scatter(const int* __restrict__ nodes, int* __restrict__ posIdx) {
  int t = blockIdx.x * 256 + threadIdx.x;
  if (t < S * NSUB) {
    int s = t / NSUB, i = t - s * NSUB;
    posIdx[nodes[t] * S + s] = i;
  }
}

// ---------------- Pt1 = (emb[nodes] @ W1)^T bf16
__global__ __launch_bounds__(256) void k_feat_w1(const int* __restrict__ nodes,
                                                 const float* __restrict__ emb,
                                                 const float* __restrict__ W1,
                                                 short* __restrict__ Pt) {
  __shared__ __align__(16) float feat[16][F];
  __shared__ float tr[64][17];
  int t = threadIdx.x;
  int s = blockIdx.x / 250;
  int i0 = (blockIdx.x - s * 250) * 16;
  int gr0 = blockIdx.x * 16;
  int lr = t >> 4, lc = (t & 15) * 8;
  int n = nodes[gr0 + lr];
  *(f32x4*)&feat[lr][lc]     = *(const f32x4*)(emb + (size_t)n * F + lc);
  *(f32x4*)&feat[lr][lc + 4] = *(const f32x4*)(emb + (size_t)n * F + lc + 4);
  __syncthreads();
  int j = t & 63, ig = t >> 6;
  float acc[4] = {0.f, 0.f, 0.f, 0.f};
  for (int k = 0; k < F; ++k) {
    float w = W1[k * HID + j];
    #pragma unroll
    for (int i = 0; i < 4; ++i) acc[i] += feat[ig * 4 + i][k] * w;
  }
  #pragma unroll
  for (int i = 0; i < 4; ++i) tr[j][ig * 4 + i] = acc[i];
  __syncthreads();
  int jr = t >> 2, seg = (t & 3) * 4;
  bf16x4 o;
  #pragma unroll
  for (int u = 0; u < 4; ++u) o[u] = f2bf(tr[jr][seg + u]);
  *(bf16x4*)(Pt + ((size_t)s * HID + jr) * NSUB + i0 + seg) = o;
}

// ---------------- layer-1 adj GEMM: LDS-staged fp32 adj, memoizes bf16 adjb (NT)
// grid 1008: s=bid&7, rest=bid>>3: z=rest&1, mb=rest>>1. block 256 = 4 waves.
__global__ __launch_bounds__(256) void k_adj(const float* __restrict__ adj,
                                             const short* __restrict__ Pt,
                                             short* __restrict__ adjb,
                                             float* __restrict__ part) {
  __shared__ __align__(16) float As[2][64 * 32];   // row*128B, chunk-swizzled
  __shared__ __align__(16) short Bs[2][64 * 32];   // col*64B, chunk-swizzled
  int bid = blockIdx.x;
  int s = bid & 7;
  int rest = bid >> 3;
  int z = rest & 1, mb = rest >> 1;
  int ks_ = z ? KSPL : 0, ke_ = z ? NSUB : KSPL;
  int tid = threadIdx.x;
  int w = tid >> 6, lane = tid & 63, l15 = lane & 15, g = lane >> 4;
  int m0 = mb * 64;
  const float* adjS = adj + (size_t)s * NSUB * NSUB;
  const short* PtS  = Pt  + (size_t)s * HID * NSUB;

  // staging maps
  int arow0 = tid >> 3;
  int aslot = tid & 7;
  int r0g = m0 + arow0;        r0g = r0g < NSUB ? r0g : NSUB - 1;
  int r1g = m0 + 32 + arow0;   r1g = r1g < NSUB ? r1g : NSUB - 1;
  int c0 = aslot ^ (arow0 & 7);
  int c1 = aslot ^ ((32 + arow0) & 7);
  const float* asrc0 = adjS + (size_t)r0g * NSUB + c0 * 4;
  const float* asrc1 = adjS + (size_t)r1g * NSUB + c1 * 4;
  int bcol  = tid >> 2;
  int bchunk = (tid & 3) ^ (bcol & 3);
  const short* bsrc0 = PtS + (size_t)bcol * NSUB + bchunk * 8;

  char* As0 = (char*)&As[0][0];
  char* Bs0 = (char*)&Bs[0][0];
  int wb = w * 1024;

  // fragment-read byte offsets (swizzled)
  int arow = w * 16 + l15;
  int fa0 = arow * 128 + (((g * 2)     ^ (arow & 7)) * 16);
  int fa1 = arow * 128 + (((g * 2 + 1) ^ (arow & 7)) * 16);
  int fb[4];
  #pragma unroll
  for (int nf = 0; nf < 4; ++nf) {
    int col = nf * 16 + l15;
    fb[nf] = col * 64 + ((g ^ (col & 3)) * 16);
  }

  // memoize-store target (logical row; guarded)
  int grow = m0 + arow;
  short* abase = adjb + (size_t)s * NSUB * NSUB + (size_t)(grow < NSUB ? grow : 0) * NSUB + g * 8;
  bool doStore = grow < NSUB;

  f32x4 acc[4];
  #pragma unroll
  for (int nf = 0; nf < 4; ++nf) acc[nf] = (f32x4){0.f, 0.f, 0.f, 0.f};

  // prologue: stage first tile into buf 0
  gload16(asrc0 + ks_, As0 + 0    + wb);
  gload16(asrc1 + ks_, As0 + 4096 + wb);
  gload16(bsrc0 + ks_, Bs0 + wb);

  int nsteps = (ke_ - ks_) >> 5;
  for (int t = 0; t < nsteps; ++t) {
    __syncthreads();
    int cur = t & 1;
    if (t + 1 < nsteps) {
      int kn = ks_ + (t + 1) * 32;
      int nb  = (cur ^ 1) * 8192;
      int nbs = (cur ^ 1) * 4096;
      gload16(asrc0 + kn, As0 + nb + 0    + wb);
      gload16(asrc1 + kn, As0 + nb + 4096 + wb);
      gload16(bsrc0 + kn, Bs0 + nbs + wb);
    }
    const char* Ab = As0 + cur * 8192;
    const char* Bb = Bs0 + cur * 4096;
    f32x4 a0 = *(const f32x4*)(Ab + fa0);
    f32x4 a1 = *(const f32x4*)(Ab + fa1);
    bf16x8 afr;
    afr[0] = f2bf(a0.x); afr[1] = f2bf(a0.y); afr[2] = f2bf(a0.z); afr[3] = f2bf(a0.w);
    afr[4] = f2bf(a1.x); afr[5] = f2bf(a1.y); afr[6] = f2bf(a1.z); afr[7] = f2bf(a1.w);
    // memoize bf16 adj for layer 2 (k = ks_+t*32 + g*8, 16B NT store)
    if (doStore)
      __builtin_nontemporal_store(afr, (bf16x8*)(abase + ks_ + t * 32));
    bf16x8 b0 = *(const bf16x8*)(Bb + fb[0]);
    bf16x8 b1 = *(const bf16x8*)(Bb + fb[1]);
    bf16x8 b2 = *(const bf16x8*)(Bb + fb[2]);
    bf16x8 b3 = *(const bf16x8*)(Bb + fb[3]);
    acc[0] = __builtin_amdgcn_mfma_f32_16x16x32_bf16(afr, b0, acc[0], 0, 0, 0);
    acc[1] = __builtin_amdgcn_mfma_f32_16x16x32_bf16(afr, b1, acc[1], 0, 0, 0);
    acc[2] = __builtin_amdgcn_mfma_f32_16x16x32_bf16(afr, b2, acc[2], 0, 0, 0);
    acc[3] = __builtin_amdgcn_mfma_f32_16x16x32_bf16(afr, b3, acc[3], 0, 0, 0);
  }

  float* P = part + (size_t)(z * S + s) * NSUB * HID;
  #pragma unroll
  for (int nf = 0; nf < 4; ++nf) {
    int col = nf * 16 + l15;
    #pragma unroll
    for (int r = 0; r < 4; ++r) {
      int row = m0 + w * 16 + g * 4 + r;
      if (row < NSUB) P[(size_t)row * HID + col] = acc[nf][r];
    }
  }
}

// ---------------- layer-2 adj GEMM on bf16 adjb: A-tile 4KB/step, 1 gload/thread
__global__ __launch_bounds__(256) void k_adjb(const short* __restrict__ adjb,
                                              const short* __restrict__ Pt,
                                              float* __restrict__ part) {
  __shared__ __align__(16) short As[2][64 * 32];   // row*64B, chunk^((row>>1)&3)
  __shared__ __align__(16) short Bs[2][64 * 32];   // col*64B, chunk^(col&3)
  int bid = blockIdx.x;
  int s = bid & 7;
  int rest = bid >> 3;
  int z = rest & 1, mb = rest >> 1;
  int ks_ = z ? KSPL : 0, ke_ = z ? NSUB : KSPL;
  int tid = threadIdx.x;
  int w = tid >> 6, lane = tid & 63, l15 = lane & 15, g = lane >> 4;
  int m0 = mb * 64;
  const short* adjS = adjb + (size_t)s * NSUB * NSUB;
  const short* PtS  = Pt  + (size_t)s * HID * NSUB;

  // A stage: row=tid>>2, slot=tid&3, chunk = slot ^ ((row>>1)&3)
  int arow0 = tid >> 2;
  int aslot = tid & 3;
  int rg = m0 + arow0; rg = rg < NSUB ? rg : NSUB - 1;
  int ac = aslot ^ ((arow0 >> 1) & 3);
  const short* asrc = adjS + (size_t)rg * NSUB + ac * 8;
  // B stage: same as layer 1
  int bcol = tid >> 2;
  int bchunk = (tid & 3) ^ (bcol & 3);
  const short* bsrc = PtS + (size_t)bcol * NSUB + bchunk * 8;

  char* As0 = (char*)&As[0][0];
  char* Bs0 = (char*)&Bs[0][0];
  int wb = w * 1024;

  int arow = w * 16 + l15;
  int fa = arow * 64 + ((g ^ ((arow >> 1) & 3)) * 16);
  int fb[4];
  #pragma unroll
  for (int nf = 0; nf < 4; ++nf) {
    int col = nf * 16 + l15;
    fb[nf] = col * 64 + ((g ^ (col & 3)) * 16);
  }

  f32x4 acc[4];
  #pragma unroll
  for (int nf = 0; nf < 4; ++nf) acc[nf] = (f32x4){0.f, 0.f, 0.f, 0.f};

  gload16(asrc + ks_, As0 + wb);
  gload16(bsrc + ks_, Bs0 + wb);

  int nsteps = (ke_ - ks_) >> 5;
  for (int t = 0; t < nsteps; ++t) {
    __syncthreads();
    int cur = t & 1;
    if (t + 1 < nsteps) {
      int kn = ks_ + (t + 1) * 32;
      int nx = (cur ^ 1) * 4096;
      gload16(asrc + kn, As0 + nx + wb);
      gload16(bsrc + kn, Bs0 + nx + wb);
    }
    const char* Ab = As0 + cur * 4096;
    const char* Bb = Bs0 + cur * 4096;
    bf16x8 afr = *(const bf16x8*)(Ab + fa);
    bf16x8 b0 = *(const bf16x8*)(Bb + fb[0]);
    bf16x8 b1 = *(const bf16x8*)(Bb + fb[1]);
    bf16x8 b2 = *(const bf16x8*)(Bb + fb[2]);
    bf16x8 b3 = *(const bf16x8*)(Bb + fb[3]);
    acc[0] = __builtin_amdgcn_mfma_f32_16x16x32_bf16(afr, b0, acc[0], 0, 0, 0);
    acc[1] = __builtin_amdgcn_mfma_f32_16x16x32_bf16(afr, b1, acc[1], 0, 0, 0);
    acc[2] = __builtin_amdgcn_mfma_f32_16x16x32_bf16(afr, b2, acc[2], 0, 0, 0);
    acc[3] = __builtin_amdgcn_mfma_f32_16x16x32_bf16(afr, b3, acc[3], 0, 0, 0);
  }

  float* P = part + (size_t)(z * S + s) * NSUB * HID;
  #pragma unroll
  for (int nf = 0; nf < 4; ++nf) {
    int col = nf * 16 + l15;
    #pragma unroll
    for (int r = 0; r < 4; ++r) {
      int row = m0 + w * 16 + g * 4 + r;
      if (row < NSUB) P[(size_t)row * HID + col] = acc[nf][r];
    }
  }
}

// ---------------- reduce layer-1 partials (x2) + bias + relu, fused h@W2 -> Pt2 (bf16 ^T)
__global__ __launch_bounds__(256) void k_reduce1(const float* __restrict__ part,
                                                 const float* __restrict__ b1,
                                                 const float* __restrict__ W2,
                                                 short* __restrict__ Pt2) {
  __shared__ float h[32][65];
  int bid = blockIdx.x;
  int s = bid / 125, i0 = (bid - s * 125) * 32;
  int t = threadIdx.x;
  int r = t >> 3, c8 = (t & 7) * 8;
  const size_t zs = (size_t)S * NSUB * HID;
  const float* P0 = part + ((size_t)s * NSUB + i0 + r) * HID + c8;
  #pragma unroll
  for (int u = 0; u < 8; ++u)
    h[r][c8 + u] = fmaxf(P0[u] + P0[zs + u] + b1[c8 + u], 0.f);
  __syncthreads();
  int j = t & 63, ib = t >> 6;
  float acc[8];
  #pragma unroll
  for (int u = 0; u < 8; ++u) acc[u] = 0.f;
  for (int k = 0; k < HID; ++k) {
    float w = W2[k * HID + j];
    #pragma unroll
    for (int u = 0; u < 8; ++u) acc[u] += h[ib * 8 + u][k] * w;
  }
  bf16x8 o;
  #pragma unroll
  for (int u = 0; u < 8; ++u) o[u] = f2bf(acc[u]);
  *(bf16x8*)(Pt2 + ((size_t)s * HID + j) * NSUB + i0 + ib * 8) = o;
}

// ---------------- reduce layer-2 partials (x2) + bias + relu -> H fp32
__global__ __launch_bounds__(256) void k_reduce2(const float* __restrict__ part,
                                                 const float* __restrict__ b2,
                                                 float* __restrict__ H) {
  size_t idx = ((size_t)blockIdx.x * 256 + threadIdx.x) * 8;
  const size_t zs = (size_t)S * NSUB * HID;
  const float* P0 = part + idx;
  int c = (int)(idx & 63);
  f32x4 r0, r1;
  #pragma unroll
  for (int u = 0; u < 4; ++u) {
    r0[u] = fmaxf(P0[u]     + P0[zs + u]     + b2[c + u], 0.f);
    r1[u] = fmaxf(P0[4 + u] + P0[zs + 4 + u] + b2[c + 4 + u], 0.f);
  }
  *(f32x4*)(H + idx) = r0;
  *(f32x4*)(H + idx + 4) = r1;
}

// ---------------- per-node attention over snapshots -> compact Zb (bf16)
__global__ __launch_bounds__(256) void k_attn(const float* __restrict__ H,
                                              const int* __restrict__ posIdx,
                                              const float* __restrict__ Wq, const float* __restrict__ bq,
                                              const float* __restrict__ Wk, const float* __restrict__ bk,
                                              const float* __restrict__ Wv, const float* __restrict__ bv,
                                              const float* __restrict__ Wo, const float* __restrict__ bo,
                                              const float* __restrict__ te,
                                              short* __restrict__ Zb) {
  __shared__ __align__(16) float xk[4][S][HID];
  __shared__ __align__(16) float qs[4][S][HID];
  __shared__ __align__(16) float ks[4][S][HID];
  __shared__ __align__(16) float vs[4][S][HID];
  __shared__ __align__(16) float os[4][S][HID];
  int w = threadIdx.x >> 6;
  int lane = threadIdx.x & 63;
  int n = blockIdx.x * 4 + w;
  int pi[S];
  #pragma unroll
  for (int s = 0; s < S; ++s) {
    pi[s] = posIdx[n * S + s];
    xk[w][s][lane] = (pi[s] >= 0) ? H[((size_t)s * NSUB + pi[s]) * HID + lane] : 0.f;
  }
  __syncthreads();
  float aq[S], ak[S], av[S];
  #pragma unroll
  for (int s = 0; s < S; ++s) { aq[s] = bq[lane]; ak[s] = bk[lane]; av[s] = bv[lane]; }
  for (int k = 0; k < HID; ++k) {
    float wq = Wq[k*HID + lane], wk_ = Wk[k*HID + lane], wv = Wv[k*HID + lane];
    #pragma unroll
    for (int s = 0; s < S; ++s) {
      float xv = xk[w][s][k];
      aq[s] += xv * wq; ak[s] += xv * wk_; av[s] += xv * wv;
    }
  }
  const float qscale = 0.35355339059327373f;
  #pragma unroll
  for (int s = 0; s < S; ++s) {
    qs[w][s][lane] = aq[s] * qscale;
    ks[w][s][lane] = ak[s];
    vs[w][s][lane] = av[s];
  }
  __syncthreads();
  int h = lane >> 3, sq = lane & 7;
  f32x4 q0 = *(const f32x4*)&qs[w][sq][h * DH];
  f32x4 q1 = *(const f32x4*)&qs[w][sq][h * DH + 4];
  float sc[S];
  #pragma unroll
  for (int t = 0; t < S; ++t) {
    f32x4 k0v = *(const f32x4*)&ks[w][t][h * DH];
    f32x4 k1v = *(const f32x4*)&ks[w][t][h * DH + 4];
    float d = q0.x*k0v.x + q0.y*k0v.y + q0.z*k0v.z + q0.w*k0v.w
            + q1.x*k1v.x + q1.y*k1v.y + q1.z*k1v.z + q1.w*k1v.w;
    sc[t] = d + te[(t - sq + S - 1) * NH + h];
  }
  float m = sc[0];
  #pragma unroll
  for (int t = 1; t < S; ++t) m = fmaxf(m, sc[t]);
  float sum = 0.f;
  #pragma unroll
  for (int t = 0; t < S; ++t) { sc[t] = expf(sc[t] - m); sum += sc[t]; }
  float inv = 1.f / sum;
  f32x4 o0 = (f32x4){0.f,0.f,0.f,0.f}, o1 = (f32x4){0.f,0.f,0.f,0.f};
  #pragma unroll
  for (int t = 0; t < S; ++t) {
    f32x4 v0 = *(const f32x4*)&vs[w][t][h * DH];
    f32x4 v1 = *(const f32x4*)&vs[w][t][h * DH + 4];
    #pragma unroll
    for (int u = 0; u < 4; ++u) { o0[u] += sc[t] * v0[u]; o1[u] += sc[t] * v1[u]; }
  }
  #pragma unroll
  for (int u = 0; u < 4; ++u) { o0[u] *= inv; o1[u] *= inv; }
  *(f32x4*)&os[w][sq][h * DH]     = o0;
  *(f32x4*)&os[w][sq][h * DH + 4] = o1;
  __syncthreads();
  float ao[S];
  #pragma unroll
  for (int s = 0; s < S; ++s) ao[s] = bo[lane];
  for (int k = 0; k < HID; ++k) {
    float wo = Wo[k*HID + lane];
    #pragma unroll
    for (int s = 0; s < S; ++s) ao[s] += os[w][s][k] * wo;
  }
  #pragma unroll
  for (int s = 0; s < S; ++s)
    if (pi[s] >= 0) Zb[((size_t)s * NSUB + pi[s]) * HID + lane] = f2bf(ao[s]);
}

// ---------------- out[s] = Z[s] @ Z[s]^T, XCD swizzle, LDS-transposed dwordx4 NT stores
__global__ __launch_bounds__(256) void k_dec(const short* __restrict__ Zb,
                                             float* __restrict__ out) {
  __shared__ __align__(16) float tr[4][16][68];
  int bid = blockIdx.x;
  int s = bid & 7;
  int tt = bid >> 3;
  int by = tt / 63, bx = tt - by * 63;
  int wave = threadIdx.x >> 6, lane = threadIdx.x & 63;
  int l15 = lane & 15, g = lane >> 4;
  int m0 = by * 64 + wave * 16;
  int n0 = bx * 64;
  const short* ZS = Zb + (size_t)s * NSUB * HID;
  int mrow = m0 + l15;
  int mc = mrow < NSUB ? mrow : NSUB - 1;
  bf16x8 a0 = *(const bf16x8*)(ZS + (size_t)mc * HID + g * 8);
  bf16x8 a1 = *(const bf16x8*)(ZS + (size_t)mc * HID + 32 + g * 8);
  f32x4 acc[4];
  #pragma unroll
  for (int nf = 0; nf < 4; ++nf) acc[nf] = (f32x4){0.f, 0.f, 0.f, 0.f};
  #pragma unroll
  for (int nf = 0; nf < 4; ++nf) {
    int ncol = n0 + nf * 16 + l15;
    int nc = ncol < NSUB ? ncol : NSUB - 1;
    bf16x8 b0 = *(const bf16x8*)(ZS + (size_t)nc * HID + g * 8);
    bf16x8 b1 = *(const bf16x8*)(ZS + (size_t)nc * HID + 32 + g * 8);
    acc[nf] = __builtin_amdgcn_mfma_f32_16x16x32_bf16(a0, b0, acc[nf], 0, 0, 0);
    acc[nf] = __builtin_amdgcn_mfma_f32_16x16x32_bf16(a1, b1, acc[nf], 0, 0, 0);
  }
  #pragma unroll
  for (int nf = 0; nf < 4; ++nf)
    #pragma unroll
    for (int r = 0; r < 4; ++r)
      tr[wave][g * 4 + r][nf * 16 + l15] = acc[nf][r];
  __syncthreads();
  float* outS = out + (size_t)s * NSUB * NSUB;
  #pragma unroll
  for (int p = 0; p < 4; ++p) {
    int rr = p * 4 + g;
    int grow = m0 + rr;
    int gcol = n0 + l15 * 4;
    f32x4 v = *(const f32x4*)&tr[wave][rr][l15 * 4];
    if (grow < NSUB && gcol < NSUB)
      __builtin_nontemporal_store(v, (f32x4*)(outS + (size_t)grow * NSUB + gcol));
  }
}

extern "C" void kernel_launch(void* const* d_in, const int* in_sizes, int n_in,
                              void* d_out, int out_size, void* d_ws, size_t ws_size,
                              hipStream_t stream) {
  const int*   nodes = (const int*)d_in[0];
  const float* adj   = (const float*)d_in[1];
  const float* emb   = (const float*)d_in[2];
  const float* W1    = (const float*)d_in[3];
  const float* b1    = (const float*)d_in[4];
  const float* W2    = (const float*)d_in[5];
  const float* b2    = (const float*)d_in[6];
  const float* te    = (const float*)d_in[7];
  const float* Wq    = (const float*)d_in[8];
  const float* bq    = (const float*)d_in[9];
  const float* Wk    = (const float*)d_in[10];
  const float* bk    = (const float*)d_in[11];
  const float* Wv    = (const float*)d_in[12];
  const float* bv    = (const float*)d_in[13];
  const float* Wo    = (const float*)d_in[14];
  const float* bo    = (const float*)d_in[15];
  float* outp = (float*)d_out;

  // ws: part 16MB | H 8MB | Pt 4MB | Zb 4MB | posIdx 0.64MB | adjb 256MB (~289MB)
  float* part = (float*)d_ws;
  float* H    = part + 2 * (size_t)S * NSUB * HID;
  short* Pt   = (short*)(H + (size_t)S * NSUB * HID);
  short* Zb   = Pt + (size_t)S * HID * NSUB;
  int* posIdx = (int*)(Zb + (size_t)S * NSUB * HID);
  short* adjb = (short*)(posIdx + (size_t)NTOT * S);

  k_pos_init<<<(NTOT*S + 255)/256, 256, 0, stream>>>(posIdx);
  k_pos_scatter<<<(S*NSUB + 255)/256, 256, 0, stream>>>(nodes, posIdx);

  // GCN layer 1 (fused W2 in reduce; memoizes bf16 adjb)
  k_feat_w1<<<2000, 256, 0, stream>>>(nodes, emb, W1, Pt);
  k_adj<<<1008, 256, 0, stream>>>(adj, Pt, adjb, part);
  k_reduce1<<<1000, 256, 0, stream>>>(part, b1, W2, Pt);
  // GCN layer 2 on bf16 adjb
  k_adjb<<<1008, 256, 0, stream>>>(adjb, Pt, part);
  k_reduce2<<<1000, 256, 0, stream>>>(part, b2, H);
  // attention -> compact Z (bf16)
  k_attn<<<NTOT/4, 256, 0, stream>>>(H, posIdx, Wq, bq, Wk, bk, Wv, bv, Wo, bo, te, Zb);
  // decoder
  k_dec<<<63*63*8, 256, 0, stream>>>(Zb, outp);
}

// Round 10
// 485.433 us; speedup vs baseline: 1.2054x; 1.2054x over previous
//
#include <hip/hip_runtime.h>
#include <hip/hip_bf16.h>
#include <cstdint>

#define S 8
#define NTOT 20000
#define NSUB 4000
#define NSUBP 4032   // padded K for Pt (63 x 64); pad cols are zero
#define NST 63       // K-steps of BK=64
#define F 128
#define HID 64
#define NH 8
#define DH 8

typedef __attribute__((ext_vector_type(8))) short bf16x8;
typedef __attribute__((ext_vector_type(4))) short bf16x4;
typedef __attribute__((ext_vector_type(4))) float f32x4;

__device__ __forceinline__ short f2bf(float f) {
  union { __hip_bfloat16 h; short s; } u;
  u.h = __float2bfloat16(f);
  return u.s;
}

__device__ __forceinline__ void gload16(const void* gsrc, void* ldst) {
  __builtin_amdgcn_global_load_lds(
      (const __attribute__((address_space(1))) void*)gsrc,
      (__attribute__((address_space(3))) void*)ldst, 16, 0, 0);
}

// ---------------- position map
__global__ void k_pos_init(int* __restrict__ posIdx) {
  int t = blockIdx.x * 256 + threadIdx.x;
  if (t < NTOT * S) posIdx[t] = -1;
}

__global__ void k_pos_scatter(const int* __restrict__ nodes, int* __restrict__ posIdx) {
  int t = blockIdx.x * 256 + threadIdx.x;
  if (t < S * NSUB) {
    int s = t / NSUB, i = t - s * NSUB;
    posIdx[nodes[t] * S + s] = i;
  }
}

// ---------------- zero the K-pad columns of Pt (cols 4000..4031 for all s,j)
__global__ void k_pt_pad(short* __restrict__ Pt) {
  int t = blockIdx.x * 256 + threadIdx.x;      // 0..2047
  int seg = t >> 2, off = (t & 3) * 8;         // seg = s*64 + j
  bf16x8 z = (bf16x8){0,0,0,0,0,0,0,0};
  *(bf16x8*)(Pt + (size_t)seg * NSUBP + NSUB + off) = z;
}

// ---------------- Pt1 = (emb[nodes] @ W1)^T bf16 (stride NSUBP)
__global__ __launch_bounds__(256) void k_feat_w1(const int* __restrict__ nodes,
                                                 const float* __restrict__ emb,
                                                 const float* __restrict__ W1,
                                                 short* __restrict__ Pt) {
  __shared__ __align__(16) float feat[16][F];
  __shared__ float tr[64][17];
  int t = threadIdx.x;
  int s = blockIdx.x / 250;
  int i0 = (blockIdx.x - s * 250) * 16;
  int gr0 = blockIdx.x * 16;
  int lr = t >> 4, lc = (t & 15) * 8;
  int n = nodes[gr0 + lr];
  *(f32x4*)&feat[lr][lc]     = *(const f32x4*)(emb + (size_t)n * F + lc);
  *(f32x4*)&feat[lr][lc + 4] = *(const f32x4*)(emb + (size_t)n * F + lc + 4);
  __syncthreads();
  int j = t & 63, ig = t >> 6;
  float acc[4] = {0.f, 0.f, 0.f, 0.f};
  for (int k = 0; k < F; ++k) {
    float w = W1[k * HID + j];
    #pragma unroll
    for (int i = 0; i < 4; ++i) acc[i] += feat[ig * 4 + i][k] * w;
  }
  #pragma unroll
  for (int i = 0; i < 4; ++i) tr[j][ig * 4 + i] = acc[i];
  __syncthreads();
  int jr = t >> 2, seg = (t & 3) * 4;
  bf16x4 o;
  #pragma unroll
  for (int u = 0; u < 4; ++u) o[u] = f2bf(tr[jr][seg + u]);
  *(bf16x4*)(Pt + ((size_t)s * HID + jr) * NSUBP + i0 + seg) = o;
}

// ---------------- adj GEMM: BK=64 (256B bursts/row), LDS-staged, dbuf, no split-K
// grid 504: s=bid&7 (XCD), mb=bid>>3. block 256 = 4 waves, BM=64.
// MODE 0: write raw partial to out (layer 1). MODE 1: write relu(acc+bias) (layer 2 -> H).
template<int MODE>
__global__ __launch_bounds__(256) void k_adj(const float* __restrict__ adj,
                                             const short* __restrict__ Pt,
                                             const float* __restrict__ bias,
                                             float* __restrict__ out) {
  __shared__ __align__(16) float As[2][64 * 64];   // row*256B, chunk^(row&7) swizzle
  __shared__ __align__(16) short Bs[2][64 * 64];   // col*128B, chunk^(col&7) swizzle
  int bid = blockIdx.x;
  int s = bid & 7;
  int mb = bid >> 3;
  int tid = threadIdx.x;
  int w = tid >> 6, lane = tid & 63, l15 = lane & 15, g = lane >> 4;
  int m0 = mb * 64;
  const float* adjS = adj + (size_t)s * NSUB * NSUB;
  const short* PtS  = Pt  + (size_t)s * HID * NSUBP;

  // ---- A staging map: 4 rounds; round p: lane of wave w -> row p*16 + w*4 + (lane>>4),
  //      physical slot lane&15 holds logical chunk (slot&8)|((slot&7)^(row&7)).
  int rbase = w * 4 + (lane >> 4);            // 0..15, same all rounds
  int sigA = l15;
  int clogA = (sigA & 8) | ((sigA & 7) ^ (rbase & 7));   // row&7 == rbase&7 (p*16 % 8 == 0)
  int acolf = clogA * 4;                      // float col offset within row
  const float* arow[4];
  #pragma unroll
  for (int p = 0; p < 4; ++p) {
    int rg = m0 + p * 16 + rbase;
    rg = rg < NSUB ? rg : NSUB - 1;
    arow[p] = adjS + (size_t)rg * NSUB;
  }
  // ---- B staging map: 2 rounds; round p: col p*32 + w*8 + (lane>>3), slot lane&7
  int sigB = lane & 7;
  int clogB = sigB ^ ((lane >> 3) & 7);
  const short* bsrc[2];
  #pragma unroll
  for (int p = 0; p < 2; ++p) {
    int col = p * 32 + w * 8 + (lane >> 3);
    bsrc[p] = PtS + (size_t)col * NSUBP + clogB * 8;
  }

  char* As0 = (char*)&As[0][0];
  char* Bs0 = (char*)&Bs[0][0];
  int wb = w * 1024;

  // ---- fragment-read byte offsets
  int arowf = w * 16 + l15;                   // wave's output row (0..63)
  int aoff = arowf * 256 + (((2 * g) ^ (arowf & 7)) * 16);
  int boff[4];
  #pragma unroll
  for (int nf = 0; nf < 4; ++nf) {
    int col = nf * 16 + l15;
    boff[nf] = col * 128 + ((g ^ (col & 7)) * 16);
  }

  f32x4 acc[4];
  #pragma unroll
  for (int nf = 0; nf < 4; ++nf) acc[nf] = (f32x4){0.f, 0.f, 0.f, 0.f};

  // ---- prologue: stage step 0 into buf 0 (kn=0: all cols in-bounds)
  #pragma unroll
  for (int p = 0; p < 4; ++p)
    gload16(arow[p] + acolf, As0 + p * 4096 + wb);
  #pragma unroll
  for (int p = 0; p < 2; ++p)
    gload16(bsrc[p], Bs0 + p * 4096 + wb);

  for (int t = 0; t < NST; ++t) {
    __syncthreads();                           // drains vmcnt -> buf (t&1) ready
    int cur = t & 1;
    if (t + 1 < NST) {
      int kn = (t + 1) * 64;
      bool ok = (kn + acolf) < NSUB;           // pad cols: redirect in-bounds (B=0 there)
      const char* nA = As0 + (cur ^ 1) * 16384;
      const char* nB = Bs0 + (cur ^ 1) * 8192;
      #pragma unroll
      for (int p = 0; p < 4; ++p)
        gload16(ok ? (arow[p] + kn + acolf) : arow[p], (void*)(nA + p * 4096 + wb));
      #pragma unroll
      for (int p = 0; p < 2; ++p)
        gload16(bsrc[p] + kn, (void*)(nB + p * 4096 + wb));
    }
    const char* Ab = As0 + cur * 16384;
    const char* Bb = Bs0 + cur * 8192;
    f32x4 a0 = *(const f32x4*)(Ab + aoff);
    f32x4 a1 = *(const f32x4*)(Ab + (aoff ^ 16));
    f32x4 a2 = *(const f32x4*)(Ab + 128 + aoff);
    f32x4 a3 = *(const f32x4*)(Ab + 128 + (aoff ^ 16));
    bf16x8 af0, af1;
    af0[0] = f2bf(a0.x); af0[1] = f2bf(a0.y); af0[2] = f2bf(a0.z); af0[3] = f2bf(a0.w);
    af0[4] = f2bf(a1.x); af0[5] = f2bf(a1.y); af0[6] = f2bf(a1.z); af0[7] = f2bf(a1.w);
    af1[0] = f2bf(a2.x); af1[1] = f2bf(a2.y); af1[2] = f2bf(a2.z); af1[3] = f2bf(a2.w);
    af1[4] = f2bf(a3.x); af1[5] = f2bf(a3.y); af1[6] = f2bf(a3.z); af1[7] = f2bf(a3.w);
    #pragma unroll
    for (int nf = 0; nf < 4; ++nf) {
      bf16x8 b0 = *(const bf16x8*)(Bb + boff[nf]);
      bf16x8 b1 = *(const bf16x8*)(Bb + (boff[nf] ^ 64));
      acc[nf] = __builtin_amdgcn_mfma_f32_16x16x32_bf16(af0, b0, acc[nf], 0, 0, 0);
      acc[nf] = __builtin_amdgcn_mfma_f32_16x16x32_bf16(af1, b1, acc[nf], 0, 0, 0);
    }
  }

  float* P = out + (size_t)s * NSUB * HID;
  #pragma unroll
  for (int nf = 0; nf < 4; ++nf) {
    int col = nf * 16 + l15;
    float bv = (MODE == 1) ? bias[col] : 0.f;
    #pragma unroll
    for (int r = 0; r < 4; ++r) {
      int row = m0 + w * 16 + g * 4 + r;
      if (row < NSUB) {
        if (MODE == 1) P[(size_t)row * HID + col] = fmaxf(acc[nf][r] + bv, 0.f);
        else           P[(size_t)row * HID + col] = acc[nf][r];
      }
    }
  }
}

// ---------------- reduce layer-1 partial + bias + relu, fused h@W2 -> Pt2 (bf16 ^T, NSUBP)
__global__ __launch_bounds__(256) void k_reduce1(const float* __restrict__ part,
                                                 const float* __restrict__ b1,
                                                 const float* __restrict__ W2,
                                                 short* __restrict__ Pt2) {
  __shared__ float h[32][65];
  int bid = blockIdx.x;
  int s = bid / 125, i0 = (bid - s * 125) * 32;
  int t = threadIdx.x;
  int r = t >> 3, c8 = (t & 7) * 8;
  const float* P0 = part + ((size_t)s * NSUB + i0 + r) * HID + c8;
  #pragma unroll
  for (int u = 0; u < 8; ++u)
    h[r][c8 + u] = fmaxf(P0[u] + b1[c8 + u], 0.f);
  __syncthreads();
  int j = t & 63, ib = t >> 6;
  float acc[8];
  #pragma unroll
  for (int u = 0; u < 8; ++u) acc[u] = 0.f;
  for (int k = 0; k < HID; ++k) {
    float w = W2[k * HID + j];
    #pragma unroll
    for (int u = 0; u < 8; ++u) acc[u] += h[ib * 8 + u][k] * w;
  }
  bf16x8 o;
  #pragma unroll
  for (int u = 0; u < 8; ++u) o[u] = f2bf(acc[u]);
  *(bf16x8*)(Pt2 + ((size_t)s * HID + j) * NSUBP + i0 + ib * 8) = o;
}

// ---------------- per-node attention over snapshots -> compact Zb (bf16)
__global__ __launch_bounds__(256) void k_attn(const float* __restrict__ H,
                                              const int* __restrict__ posIdx,
                                              const float* __restrict__ Wq, const float* __restrict__ bq,
                                              const float* __restrict__ Wk, const float* __restrict__ bk,
                                              const float* __restrict__ Wv, const float* __restrict__ bv,
                                              const float* __restrict__ Wo, const float* __restrict__ bo,
                                              const float* __restrict__ te,
                                              short* __restrict__ Zb) {
  __shared__ __align__(16) float xk[4][S][HID];
  __shared__ __align__(16) float qs[4][S][HID];
  __shared__ __align__(16) float ks[4][S][HID];
  __shared__ __align__(16) float vs[4][S][HID];
  __shared__ __align__(16) float os[4][S][HID];
  int w = threadIdx.x >> 6;
  int lane = threadIdx.x & 63;
  int n = blockIdx.x * 4 + w;
  int pi[S];
  #pragma unroll
  for (int s = 0; s < S; ++s) {
    pi[s] = posIdx[n * S + s];
    xk[w][s][lane] = (pi[s] >= 0) ? H[((size_t)s * NSUB + pi[s]) * HID + lane] : 0.f;
  }
  __syncthreads();
  float aq[S], ak[S], av[S];
  #pragma unroll
  for (int s = 0; s < S; ++s) { aq[s] = bq[lane]; ak[s] = bk[lane]; av[s] = bv[lane]; }
  for (int k = 0; k < HID; ++k) {
    float wq = Wq[k*HID + lane], wk_ = Wk[k*HID + lane], wv = Wv[k*HID + lane];
    #pragma unroll
    for (int s = 0; s < S; ++s) {
      float xv = xk[w][s][k];
      aq[s] += xv * wq; ak[s] += xv * wk_; av[s] += xv * wv;
    }
  }
  const float qscale = 0.35355339059327373f;
  #pragma unroll
  for (int s = 0; s < S; ++s) {
    qs[w][s][lane] = aq[s] * qscale;
    ks[w][s][lane] = ak[s];
    vs[w][s][lane] = av[s];
  }
  __syncthreads();
  int h = lane >> 3, sq = lane & 7;
  f32x4 q0 = *(const f32x4*)&qs[w][sq][h * DH];
  f32x4 q1 = *(const f32x4*)&qs[w][sq][h * DH + 4];
  float sc[S];
  #pragma unroll
  for (int t = 0; t < S; ++t) {
    f32x4 k0v = *(const f32x4*)&ks[w][t][h * DH];
    f32x4 k1v = *(const f32x4*)&ks[w][t][h * DH + 4];
    float d = q0.x*k0v.x + q0.y*k0v.y + q0.z*k0v.z + q0.w*k0v.w
            + q1.x*k1v.x + q1.y*k1v.y + q1.z*k1v.z + q1.w*k1v.w;
    sc[t] = d + te[(t - sq + S - 1) * NH + h];
  }
  float m = sc[0];
  #pragma unroll
  for (int t = 1; t < S; ++t) m = fmaxf(m, sc[t]);
  float sum = 0.f;
  #pragma unroll
  for (int t = 0; t < S; ++t) { sc[t] = expf(sc[t] - m); sum += sc[t]; }
  float inv = 1.f / sum;
  f32x4 o0 = (f32x4){0.f,0.f,0.f,0.f}, o1 = (f32x4){0.f,0.f,0.f,0.f};
  #pragma unroll
  for (int t = 0; t < S; ++t) {
    f32x4 v0 = *(const f32x4*)&vs[w][t][h * DH];
    f32x4 v1 = *(const f32x4*)&vs[w][t][h * DH + 4];
    #pragma unroll
    for (int u = 0; u < 4; ++u) { o0[u] += sc[t] * v0[u]; o1[u] += sc[t] * v1[u]; }
  }
  #pragma unroll
  for (int u = 0; u < 4; ++u) { o0[u] *= inv; o1[u] *= inv; }
  *(f32x4*)&os[w][sq][h * DH]     = o0;
  *(f32x4*)&os[w][sq][h * DH + 4] = o1;
  __syncthreads();
  float ao[S];
  #pragma unroll
  for (int s = 0; s < S; ++s) ao[s] = bo[lane];
  for (int k = 0; k < HID; ++k) {
    float wo = Wo[k*HID + lane];
    #pragma unroll
    for (int s = 0; s < S; ++s) ao[s] += os[w][s][k] * wo;
  }
  #pragma unroll
  for (int s = 0; s < S; ++s)
    if (pi[s] >= 0) Zb[((size_t)s * NSUB + pi[s]) * HID + lane] = f2bf(ao[s]);
}

// ---------------- out[s] = Z[s] @ Z[s]^T, XCD swizzle, LDS-transposed dwordx4 NT stores
__global__ __launch_bounds__(256) void k_dec(const short* __restrict__ Zb,
                                             float* __restrict__ out) {
  __shared__ __align__(16) float tr[4][16][68];
  int bid = blockIdx.x;
  int s = bid & 7;
  int tt = bid >> 3;
  int by = tt / 63, bx = tt - by * 63;
  int wave = threadIdx.x >> 6, lane = threadIdx.x & 63;
  int l15 = lane & 15, g = lane >> 4;
  int m0 = by * 64 + wave * 16;
  int n0 = bx * 64;
  const short* ZS = Zb + (size_t)s * NSUB * HID;
  int mrow = m0 + l15;
  int mc = mrow < NSUB ? mrow : NSUB - 1;
  bf16x8 a0 = *(const bf16x8*)(ZS + (size_t)mc * HID + g * 8);
  bf16x8 a1 = *(const bf16x8*)(ZS + (size_t)mc * HID + 32 + g * 8);
  f32x4 acc[4];
  #pragma unroll
  for (int nf = 0; nf < 4; ++nf) acc[nf] = (f32x4){0.f, 0.f, 0.f, 0.f};
  #pragma unroll
  for (int nf = 0; nf < 4; ++nf) {
    int ncol = n0 + nf * 16 + l15;
    int nc = ncol < NSUB ? ncol : NSUB - 1;
    bf16x8 b0 = *(const bf16x8*)(ZS + (size_t)nc * HID + g * 8);
    bf16x8 b1 = *(const bf16x8*)(ZS + (size_t)nc * HID + 32 + g * 8);
    acc[nf] = __builtin_amdgcn_mfma_f32_16x16x32_bf16(a0, b0, acc[nf], 0, 0, 0);
    acc[nf] = __builtin_amdgcn_mfma_f32_16x16x32_bf16(a1, b1, acc[nf], 0, 0, 0);
  }
  #pragma unroll
  for (int nf = 0; nf < 4; ++nf)
    #pragma unroll
    for (int r = 0; r < 4; ++r)
      tr[wave][g * 4 + r][nf * 16 + l15] = acc[nf][r];
  __syncthreads();
  float* outS = out + (size_t)s * NSUB * NSUB;
  #pragma unroll
  for (int p = 0; p < 4; ++p) {
    int rr = p * 4 + g;
    int grow = m0 + rr;
    int gcol = n0 + l15 * 4;
    f32x4 v = *(const f32x4*)&tr[wave][rr][l15 * 4];
    if (grow < NSUB && gcol < NSUB)
      __builtin_nontemporal_store(v, (f32x4*)(outS + (size_t)grow * NSUB + gcol));
  }
}

extern "C" void kernel_launch(void* const* d_in, const int* in_sizes, int n_in,
                              void* d_out, int out_size, void* d_ws, size_t ws_size,
                              hipStream_t stream) {
  const int*   nodes = (const int*)d_in[0];
  const float* adj   = (const float*)d_in[1];
  const float* emb   = (const float*)d_in[2];
  const float* W1    = (const float*)d_in[3];
  const float* b1    = (const float*)d_in[4];
  const float* W2    = (const float*)d_in[5];
  const float* b2    = (const float*)d_in[6];
  const float* te    = (const float*)d_in[7];
  const float* Wq    = (const float*)d_in[8];
  const float* bq    = (const float*)d_in[9];
  const float* Wk    = (const float*)d_in[10];
  const float* bk    = (const float*)d_in[11];
  const float* Wv    = (const float*)d_in[12];
  const float* bv    = (const float*)d_in[13];
  const float* Wo    = (const float*)d_in[14];
  const float* bo    = (const float*)d_in[15];
  float* outp = (float*)d_out;

  // ws: part 8MB | H 8MB | Pt (8*64*4032*2B ~ 4.13MB) | Zb 4MB | posIdx 0.64MB
  float* part = (float*)d_ws;
  float* H    = part + (size_t)S * NSUB * HID;
  short* Pt   = (short*)(H + (size_t)S * NSUB * HID);
  short* Zb   = Pt + (size_t)S * HID * NSUBP;
  int* posIdx = (int*)(Zb + (size_t)S * NSUB * HID);

  k_pos_init<<<(NTOT*S + 255)/256, 256, 0, stream>>>(posIdx);
  k_pos_scatter<<<(S*NSUB + 255)/256, 256, 0, stream>>>(nodes, posIdx);
  k_pt_pad<<<8, 256, 0, stream>>>(Pt);

  // GCN layer 1 (raw partial -> part; reduce fuses bias+relu+W2 -> Pt2)
  k_feat_w1<<<2000, 256, 0, stream>>>(nodes, emb, W1, Pt);
  k_adj<0><<<504, 256, 0, stream>>>(adj, Pt, b1, part);
  k_reduce1<<<1000, 256, 0, stream>>>(part, b1, W2, Pt);
  // GCN layer 2 (epilogue fuses bias+relu -> H directly)
  k_adj<1><<<504, 256, 0, stream>>>(adj, Pt, b2, H);
  // attention -> compact Z (bf16)
  k_attn<<<NTOT/4, 256, 0, stream>>>(H, posIdx, Wq, bq, Wk, bk, Wv, bv, Wo, bo, te, Zb);
  // decoder
  k_dec<<<63*63*8, 256, 0, stream>>>(Zb, outp);
}